// Round 5
// baseline (487.074 us; speedup 1.0000x reference)
//
#include <hip/hip_runtime.h>
#include <stdint.h>

#define B_ 4
#define T_ 1024
#define C_ 1024
#define H_ 16
#define D_ 64

typedef __bf16 bf16x8 __attribute__((ext_vector_type(8)));
typedef short  s16x8  __attribute__((ext_vector_type(8)));
typedef float  f32x4  __attribute__((ext_vector_type(4)));
typedef float  f32x2  __attribute__((ext_vector_type(2)));

// MFMA via builtin (compiler handles hazards): D = A(16x32)*B(32x16)+C, bf16 in, f32 acc.
// A-frag: lane holds A[lane&15][(lane>>4)*8 + j]
// B-frag: lane holds B[(lane>>4)*8 + j][lane&15]
// D:      lane holds D[(lane>>4)*4 + r][lane&15]
__device__ inline f32x4 mfma16(s16x8 a, s16x8 b, f32x4 c) {
    return __builtin_amdgcn_mfma_f32_16x16x32_bf16(a, b, c, 0, 0, 0);
}

// exact hi/lo split: hi = bf16(a), lo = bf16(a - hi)
__device__ inline void split_pack(f32x4 a, f32x4 b, s16x8& hi, s16x8& lo) {
    bf16x8 h, l;
    #pragma unroll
    for (int j = 0; j < 4; j++) {
        __bf16 x = (__bf16)a[j]; h[j]     = x; l[j]     = (__bf16)(a[j] - (float)x);
        __bf16 y = (__bf16)b[j]; h[j + 4] = y; l[j + 4] = (__bf16)(b[j] - (float)y);
    }
    hi = __builtin_bit_cast(s16x8, h);
    lo = __builtin_bit_cast(s16x8, l);
}

// ---------------- GEMM (3-pass split-bf16): C[M,N] = A[M,K] @ W[N,K]^T + bias ----------------
template<int MODE>
__global__ __launch_bounds__(256) void k_gemm_3p(const float* __restrict__ A,
                                                 const float* __restrict__ Bw,
                                                 const float* __restrict__ bias,
                                                 float* __restrict__ Cout,
                                                 int N, int K) {
    const int m0 = blockIdx.y * 128, n0 = blockIdx.x * 128;
    __shared__ __attribute__((aligned(16))) __bf16 Ah[128 * 40];
    __shared__ __attribute__((aligned(16))) __bf16 Al[128 * 40];
    __shared__ __attribute__((aligned(16))) __bf16 Bh[128 * 40];
    __shared__ __attribute__((aligned(16))) __bf16 Bl[128 * 40];
    const int tid = threadIdx.x, lane = tid & 63, wid = tid >> 6;
    const int wm = wid >> 1, wn = wid & 1;
    const int l15 = lane & 15, lh = lane >> 4;
    f32x4 zero = {0.f, 0.f, 0.f, 0.f};
    f32x4 acc[4][4];
    for (int i = 0; i < 4; i++) for (int j = 0; j < 4; j++) acc[i][j] = zero;
    const int r0 = tid >> 2, c8 = (tid & 3) * 8;

    for (int kk = 0; kk < K; kk += 32) {
        __syncthreads();
        #pragma unroll
        for (int g = 0; g < 128; g += 64) {
            int row = m0 + r0 + g;
            const float* ap;
            if (MODE == 0) {
                ap = A + (size_t)row * K + kk + c8;
            } else {
                int b = row >> 10, t = row & 1023;
                int col = kk + c8;
                int h = col >> 6, d = col & 63;
                ap = A + (((size_t)(b * H_ + h) * T_ + t) * D_ + d);
            }
            f32x4 a0 = *(const f32x4*)ap, a1 = *(const f32x4*)(ap + 4);
            s16x8 hi, lo; split_pack(a0, a1, hi, lo);
            *(s16x8*)&Ah[(r0 + g) * 40 + c8] = hi;
            *(s16x8*)&Al[(r0 + g) * 40 + c8] = lo;
            const float* bp = Bw + (size_t)(n0 + r0 + g) * K + kk + c8;
            f32x4 b0 = *(const f32x4*)bp, b1 = *(const f32x4*)(bp + 4);
            s16x8 bhi, blo; split_pack(b0, b1, bhi, blo);
            *(s16x8*)&Bh[(r0 + g) * 40 + c8] = bhi;
            *(s16x8*)&Bl[(r0 + g) * 40 + c8] = blo;
        }
        __syncthreads();
        s16x8 afh[4], afl[4], bfh[4], bfl[4];
        #pragma unroll
        for (int mf = 0; mf < 4; mf++) {
            afh[mf] = *(const s16x8*)&Ah[(wm * 64 + mf * 16 + l15) * 40 + lh * 8];
            afl[mf] = *(const s16x8*)&Al[(wm * 64 + mf * 16 + l15) * 40 + lh * 8];
        }
        #pragma unroll
        for (int nf = 0; nf < 4; nf++) {
            bfh[nf] = *(const s16x8*)&Bh[(wn * 64 + nf * 16 + l15) * 40 + lh * 8];
            bfl[nf] = *(const s16x8*)&Bl[(wn * 64 + nf * 16 + l15) * 40 + lh * 8];
        }
        #pragma unroll
        for (int mf = 0; mf < 4; mf++)
            #pragma unroll
            for (int nf = 0; nf < 4; nf++) {
                acc[mf][nf] = mfma16(afh[mf], bfh[nf], acc[mf][nf]);
                acc[mf][nf] = mfma16(afl[mf], bfh[nf], acc[mf][nf]);
                acc[mf][nf] = mfma16(afh[mf], bfl[nf], acc[mf][nf]);
            }
    }
    #pragma unroll
    for (int mf = 0; mf < 4; mf++)
        #pragma unroll
        for (int nf = 0; nf < 4; nf++)
            #pragma unroll
            for (int r = 0; r < 4; r++) {
                int row = m0 + wm * 64 + mf * 16 + lh * 4 + r;
                int col = n0 + wn * 64 + nf * 16 + l15;
                Cout[(size_t)row * N + col] = acc[mf][nf][r] + bias[col];
            }
}

// ---------------- RoPE + split + transpose/pack ----------------
__global__ __launch_bounds__(256) void k_rope_pack(const float* __restrict__ qkv,
                                                   const float* __restrict__ sinT,
                                                   const float* __restrict__ cosT,
                                                   __bf16* __restrict__ q_hi, __bf16* __restrict__ q_lo,
                                                   __bf16* __restrict__ k_hi, __bf16* __restrict__ k_lo,
                                                   __bf16* __restrict__ v_hi, __bf16* __restrict__ v_lo) {
    const int bh = blockIdx.x >> 4, tc = blockIdx.x & 15;
    const int b = bh >> 4, h = bh & 15;
    const int t0 = tc * 64;
    __shared__ float vt[64 * 72];
    const int tid = threadIdx.x;
    const int tl = tid >> 2, dq = (tid & 3) * 8;
    const int t = t0 + tl;
    const size_t base = ((size_t)(b * T_ + t) * 3) * C_ + h * 64;

    f32x4 s0 = *(const f32x4*)(sinT + t * 64 + dq);
    f32x4 s1 = *(const f32x4*)(sinT + t * 64 + dq + 4);
    f32x4 c0 = *(const f32x4*)(cosT + t * 64 + dq);
    f32x4 c1 = *(const f32x4*)(cosT + t * 64 + dq + 4);

    {
        f32x4 ql0 = *(const f32x4*)(qkv + base + dq);
        f32x4 ql1 = *(const f32x4*)(qkv + base + dq + 4);
        f32x4 qu0 = *(const f32x4*)(qkv + base + dq + 32);
        f32x4 qu1 = *(const f32x4*)(qkv + base + dq + 36);
        f32x4 qa0 = (ql0 * c0 - qu0 * s0) * 0.125f;
        f32x4 qa1 = (ql1 * c1 - qu1 * s1) * 0.125f;
        f32x4 qb0 = (qu0 * c0 + ql0 * s0) * 0.125f;
        f32x4 qb1 = (qu1 * c1 + ql1 * s1) * 0.125f;
        size_t qi = ((size_t)bh * T_ + t) * 64 + dq;
        s16x8 hi, lo;
        split_pack(qa0, qa1, hi, lo);
        *(s16x8*)(q_hi + qi) = hi; *(s16x8*)(q_lo + qi) = lo;
        split_pack(qb0, qb1, hi, lo);
        *(s16x8*)(q_hi + qi + 32) = hi; *(s16x8*)(q_lo + qi + 32) = lo;
        f32x4 kl0 = *(const f32x4*)(qkv + base + C_ + dq);
        f32x4 kl1 = *(const f32x4*)(qkv + base + C_ + dq + 4);
        f32x4 ku0 = *(const f32x4*)(qkv + base + C_ + dq + 32);
        f32x4 ku1 = *(const f32x4*)(qkv + base + C_ + dq + 36);
        f32x4 ka0 = kl0 * c0 - ku0 * s0;
        f32x4 ka1 = kl1 * c1 - ku1 * s1;
        f32x4 kb0 = ku0 * c0 + kl0 * s0;
        f32x4 kb1 = ku1 * c1 + kl1 * s1;
        split_pack(ka0, ka1, hi, lo);
        *(s16x8*)(k_hi + qi) = hi; *(s16x8*)(k_lo + qi) = lo;
        split_pack(kb0, kb1, hi, lo);
        *(s16x8*)(k_hi + qi + 32) = hi; *(s16x8*)(k_lo + qi + 32) = lo;
    }
    {
        f32x4 vl0 = *(const f32x4*)(qkv + base + 2 * C_ + dq);
        f32x4 vl1 = *(const f32x4*)(qkv + base + 2 * C_ + dq + 4);
        f32x4 vu0 = *(const f32x4*)(qkv + base + 2 * C_ + dq + 32);
        f32x4 vu1 = *(const f32x4*)(qkv + base + 2 * C_ + dq + 36);
        #pragma unroll
        for (int j = 0; j < 4; j++) {
            vt[tl * 72 + dq + j]      = vl0[j];
            vt[tl * 72 + dq + 4 + j]  = vl1[j];
            vt[tl * 72 + dq + 32 + j] = vu0[j];
            vt[tl * 72 + dq + 36 + j] = vu1[j];
        }
    }
    __syncthreads();
    const int d = tid >> 2, tq = (tid & 3) * 16;
    bf16x8 h0, h1, l0, l1;
    #pragma unroll
    for (int i = 0; i < 8; i++) {
        float va = vt[(tq + i) * 72 + d];
        float vb = vt[(tq + 8 + i) * 72 + d];
        __bf16 xa = (__bf16)va; h0[i] = xa; l0[i] = (__bf16)(va - (float)xa);
        __bf16 xb = (__bf16)vb; h1[i] = xb; l1[i] = (__bf16)(vb - (float)xb);
    }
    size_t vi = ((size_t)bh * 64 + d) * T_ + t0 + tq;
    *(s16x8*)(v_hi + vi)     = __builtin_bit_cast(s16x8, h0);
    *(s16x8*)(v_hi + vi + 8) = __builtin_bit_cast(s16x8, h1);
    *(s16x8*)(v_lo + vi)     = __builtin_bit_cast(s16x8, l0);
    *(s16x8*)(v_lo + vi + 8) = __builtin_bit_cast(s16x8, l1);
}

// ---------------- Attention ----------------
// Block: 512 threads (8 waves), one (b,h) x 16 q-rows. LDS: 16x1024 f32 scores (XOR-swizzled).
__global__ __launch_bounds__(512) void k_attn(const __bf16* __restrict__ q_hi, const __bf16* __restrict__ q_lo,
                                              const __bf16* __restrict__ k_hi, const __bf16* __restrict__ k_lo,
                                              const __bf16* __restrict__ v_hi, const __bf16* __restrict__ v_lo,
                                              const float* __restrict__ rel_bias,
                                              const float* __restrict__ gains,
                                              float* __restrict__ attn_out,
                                              float* __restrict__ ctx_out) {
    // bijective XCD swizzle: 4096 blocks, 8 XCDs, 512 per chunk
    const int wg = (blockIdx.x & 7) * 512 + (blockIdx.x >> 3);
    const int bh = wg >> 6, t0 = (wg & 63) * 16;
    const int b = bh >> 4, h = bh & 15;
    (void)b;
    __shared__ __attribute__((aligned(16))) float sc[16 * 1024];  // 64KB
    const int tid = threadIdx.x, lane = tid & 63, w = tid >> 6;   // w = 0..7
    const int l15 = lane & 15, lh = lane >> 4;
    f32x4 zero = {0.f, 0.f, 0.f, 0.f};

    // ---- Phase A: scores = (q*scale) @ k^T, 3-pass split. Wave w: s in [w*128, w*128+128)
    s16x8 aq0h, aq0l, aq1h, aq1l;
    {
        size_t qb = ((size_t)bh * T_ + t0 + l15) * 64 + lh * 8;
        aq0h = *(const s16x8*)(q_hi + qb); aq1h = *(const s16x8*)(q_hi + qb + 32);
        aq0l = *(const s16x8*)(q_lo + qb); aq1l = *(const s16x8*)(q_lo + qb + 32);
    }
    f32x4 acc[8];
    #pragma unroll
    for (int i = 0; i < 8; i++) acc[i] = zero;
    #pragma unroll
    for (int nf = 0; nf < 8; nf++) {
        int srow = w * 128 + nf * 16 + l15;
        size_t kb = ((size_t)bh * T_ + srow) * 64 + lh * 8;
        s16x8 kh0 = *(const s16x8*)(k_hi + kb), kh1 = *(const s16x8*)(k_hi + kb + 32);
        s16x8 kl0 = *(const s16x8*)(k_lo + kb), kl1 = *(const s16x8*)(k_lo + kb + 32);
        acc[nf] = mfma16(aq0h, kh0, acc[nf]);
        acc[nf] = mfma16(aq0l, kh0, acc[nf]);
        acc[nf] = mfma16(aq0h, kl0, acc[nf]);
        acc[nf] = mfma16(aq1h, kh1, acc[nf]);
        acc[nf] = mfma16(aq1l, kh1, acc[nf]);
        acc[nf] = mfma16(aq1h, kl1, acc[nf]);
    }
    #pragma unroll
    for (int nf = 0; nf < 8; nf++)
        #pragma unroll
        for (int r = 0; r < 4; r++) {
            int row = lh * 4 + r;
            int s = w * 128 + nf * 16 + l15;
            int xr = (row & 7) << 2;
            sc[row * 1024 + (s ^ xr)] =
                acc[nf][r] + rel_bias[((size_t)h * T_ + t0 + row) * T_ + s];
        }
    __syncthreads();

    // ---- Phase B: softmax per row (32 threads/row), write attn (f32)
    {
        const int row = tid >> 5, seg = tid & 31;
        const int xr = (row & 7) << 2;
        float* scr = sc + row * 1024;
        float m = -3.4e38f;
        #pragma unroll
        for (int i = 0; i < 8; i++) {
            f32x4 v = *(const f32x4*)&scr[(i * 128 + seg * 4) ^ xr];
            m = fmaxf(m, fmaxf(fmaxf(v[0], v[1]), fmaxf(v[2], v[3])));
        }
        #pragma unroll
        for (int o = 16; o >= 1; o >>= 1) m = fmaxf(m, __shfl_xor(m, o));
        float lsum = 0.f;
        #pragma unroll
        for (int i = 0; i < 8; i++) {
            int off = (i * 128 + seg * 4) ^ xr;
            f32x4 v = *(const f32x4*)&scr[off];
            v[0] = __expf(v[0] - m); v[1] = __expf(v[1] - m);
            v[2] = __expf(v[2] - m); v[3] = __expf(v[3] - m);
            *(f32x4*)&scr[off] = v;
            lsum += v[0] + v[1] + v[2] + v[3];
        }
        #pragma unroll
        for (int o = 16; o >= 1; o >>= 1) lsum += __shfl_xor(lsum, o);
        float inv = 1.f / lsum;
        float* arow = attn_out + ((size_t)bh * T_ + t0 + row) * T_;
        #pragma unroll
        for (int i = 0; i < 8; i++) {
            int s = i * 128 + seg * 4;
            int off = s ^ xr;
            f32x4 v = *(const f32x4*)&scr[off];
            v *= inv;
            *(f32x4*)&scr[off] = v;
            *(f32x4*)(arow + s) = v;
        }
    }
    __syncthreads();

    // ---- Phase C: PV, 3-pass split. Wave w: s in [w*128, w*128+128)
    f32x4 cacc[4];
    #pragma unroll
    for (int i = 0; i < 4; i++) cacc[i] = zero;
    const int xs = (l15 & 7) << 2;
    #pragma unroll
    for (int ks = 0; ks < 4; ks++) {
        int sbase = w * 128 + ks * 32 + lh * 8;
        const float* ap = sc + l15 * 1024;
        f32x4 a0 = *(const f32x4*)&ap[(sbase) ^ xs];
        f32x4 a1 = *(const f32x4*)&ap[(sbase + 4) ^ xs];
        s16x8 ah, al; split_pack(a0, a1, ah, al);
        #pragma unroll
        for (int nf = 0; nf < 4; nf++) {
            size_t vb = ((size_t)bh * 64 + nf * 16 + l15) * T_ + sbase;
            s16x8 vh = *(const s16x8*)(v_hi + vb);
            s16x8 vl = *(const s16x8*)(v_lo + vb);
            cacc[nf] = mfma16(ah, vh, cacc[nf]);
            cacc[nf] = mfma16(al, vh, cacc[nf]);
            cacc[nf] = mfma16(ah, vl, cacc[nf]);
        }
    }
    __syncthreads();
    // dump wave partials into sc (rows 0..7 region), then reduce + gains + write ctx
    #pragma unroll
    for (int nf = 0; nf < 4; nf++)
        #pragma unroll
        for (int r = 0; r < 4; r++)
            sc[w * 1024 + (lh * 4 + r) * 64 + nf * 16 + l15] = cacc[nf][r];
    __syncthreads();
    {
        int e0 = tid * 2;                       // 1024 outputs, 512 threads
        int crow = e0 >> 6, d = e0 & 63;
        f32x2 sm = *(const f32x2*)&sc[e0];
        #pragma unroll
        for (int w2 = 1; w2 < 8; w2++) sm += *(const f32x2*)&sc[w2 * 1024 + e0];
        float g = gains[h];
        sm[0] *= g; sm[1] *= g;
        *(f32x2*)(ctx_out + ((size_t)bh * T_ + t0 + crow) * 64 + d) = sm;
    }
}

extern "C" void kernel_launch(void* const* d_in, const int* in_sizes, int n_in,
                              void* d_out, int out_size, void* d_ws, size_t ws_size,
                              hipStream_t stream) {
    const float* x        = (const float*)d_in[0];
    const float* qkv_w    = (const float*)d_in[1];
    const float* qkv_b    = (const float*)d_in[2];
    const float* out_w    = (const float*)d_in[3];
    const float* out_b    = (const float*)d_in[4];
    const float* rel_bias = (const float*)d_in[5];
    const float* sinT     = (const float*)d_in[6];
    const float* cosT     = (const float*)d_in[7];
    const float* gains    = (const float*)d_in[8];

    float* out  = (float*)d_out;                       // [B,T,C]
    float* ctx  = out + (size_t)B_ * T_ * C_;          // [B,H,T,D]
    float* attn = ctx + (size_t)B_ * H_ * T_ * D_;     // [B,H,T,T]

    char* ws = (char*)d_ws;
    __bf16* q_hi = (__bf16*)(ws);                      // 8 MB [B,H,T,D]
    __bf16* q_lo = (__bf16*)(ws + ((size_t)8 << 20));
    __bf16* k_hi = (__bf16*)(ws + ((size_t)16 << 20));
    __bf16* k_lo = (__bf16*)(ws + ((size_t)24 << 20));
    __bf16* v_hi = (__bf16*)(ws + ((size_t)32 << 20)); // [B,H,D,T]
    __bf16* v_lo = (__bf16*)(ws + ((size_t)40 << 20));
    // qkv f32 intermediate [B,T,3C] (48 MB) lives in the attn output region:
    // fully consumed by k_rope_pack before k_attn writes attn.
    float* qkvF = attn;

    // QKV: [4096,1024] @ [3072,1024]^T + qkv_b -> qkvF [4096,3072]  (3-pass split)
    k_gemm_3p<0><<<dim3(24, 32), 256, 0, stream>>>(x, qkv_w, qkv_b, qkvF, 3072, 1024);
    // RoPE + split + pack
    k_rope_pack<<<1024, 256, 0, stream>>>(qkvF, sinT, cosT, q_hi, q_lo, k_hi, k_lo, v_hi, v_lo);
    // Attention (writes attn f32, ctx f32)
    k_attn<<<4096, 512, 0, stream>>>(q_hi, q_lo, k_hi, k_lo, v_hi, v_lo,
                                     rel_bias, gains, attn, ctx);
    // Output projection: merged(=ctx perm) [4096,1024] @ [1024,1024]^T + out_b -> out
    k_gemm_3p<1><<<dim3(8, 32), 256, 0, stream>>>(ctx, out_w, out_b, out, 1024, 1024);
}

// Round 6
// 428.811 us; speedup vs baseline: 1.1359x; 1.1359x over previous
//
#include <hip/hip_runtime.h>
#include <stdint.h>

#define B_ 4
#define T_ 1024
#define C_ 1024
#define H_ 16
#define D_ 64

typedef __bf16 bf16x8 __attribute__((ext_vector_type(8)));
typedef short  s16x8  __attribute__((ext_vector_type(8)));
typedef float  f32x4  __attribute__((ext_vector_type(4)));
typedef float  f32x2  __attribute__((ext_vector_type(2)));

// MFMA: D = A(16x32)*B(32x16)+C, bf16 in, f32 acc.
// A-frag: lane holds A[lane&15][(lane>>4)*8 + j]
// B-frag: lane holds B[(lane>>4)*8 + j][lane&15]
// D:      lane holds D[(lane>>4)*4 + r][lane&15]
__device__ inline f32x4 mfma16(s16x8 a, s16x8 b, f32x4 c) {
    return __builtin_amdgcn_mfma_f32_16x16x32_bf16(a, b, c, 0, 0, 0);
}

// exact hi/lo split: hi = bf16(a), lo = bf16(a - hi)
__device__ inline void split_pack(f32x4 a, f32x4 b, s16x8& hi, s16x8& lo) {
    bf16x8 h, l;
    #pragma unroll
    for (int j = 0; j < 4; j++) {
        __bf16 x = (__bf16)a[j]; h[j]     = x; l[j]     = (__bf16)(a[j] - (float)x);
        __bf16 y = (__bf16)b[j]; h[j + 4] = y; l[j + 4] = (__bf16)(b[j] - (float)y);
    }
    hi = __builtin_bit_cast(s16x8, h);
    lo = __builtin_bit_cast(s16x8, l);
}

// ---------------- GEMM (3-pass split-bf16): C[M,N] = A[M,K] @ W[N,K]^T + bias ----------------
template<int MODE>
__global__ __launch_bounds__(256) void k_gemm_3p(const float* __restrict__ A,
                                                 const float* __restrict__ Bw,
                                                 const float* __restrict__ bias,
                                                 float* __restrict__ Cout,
                                                 int N, int K) {
    const int m0 = blockIdx.y * 128, n0 = blockIdx.x * 128;
    __shared__ __attribute__((aligned(16))) __bf16 Ah[128 * 40];
    __shared__ __attribute__((aligned(16))) __bf16 Al[128 * 40];
    __shared__ __attribute__((aligned(16))) __bf16 Bh[128 * 40];
    __shared__ __attribute__((aligned(16))) __bf16 Bl[128 * 40];
    const int tid = threadIdx.x, lane = tid & 63, wid = tid >> 6;
    const int wm = wid >> 1, wn = wid & 1;
    const int l15 = lane & 15, lh = lane >> 4;
    f32x4 zero = {0.f, 0.f, 0.f, 0.f};
    f32x4 acc[4][4];
    for (int i = 0; i < 4; i++) for (int j = 0; j < 4; j++) acc[i][j] = zero;
    const int r0 = tid >> 2, c8 = (tid & 3) * 8;

    for (int kk = 0; kk < K; kk += 32) {
        __syncthreads();
        #pragma unroll
        for (int g = 0; g < 128; g += 64) {
            int row = m0 + r0 + g;
            const float* ap;
            if (MODE == 0) {
                ap = A + (size_t)row * K + kk + c8;
            } else {
                int b = row >> 10, t = row & 1023;
                int col = kk + c8;
                int h = col >> 6, d = col & 63;
                ap = A + (((size_t)(b * H_ + h) * T_ + t) * D_ + d);
            }
            f32x4 a0 = *(const f32x4*)ap, a1 = *(const f32x4*)(ap + 4);
            s16x8 hi, lo; split_pack(a0, a1, hi, lo);
            *(s16x8*)&Ah[(r0 + g) * 40 + c8] = hi;
            *(s16x8*)&Al[(r0 + g) * 40 + c8] = lo;
            const float* bp = Bw + (size_t)(n0 + r0 + g) * K + kk + c8;
            f32x4 b0 = *(const f32x4*)bp, b1 = *(const f32x4*)(bp + 4);
            s16x8 bhi, blo; split_pack(b0, b1, bhi, blo);
            *(s16x8*)&Bh[(r0 + g) * 40 + c8] = bhi;
            *(s16x8*)&Bl[(r0 + g) * 40 + c8] = blo;
        }
        __syncthreads();
        s16x8 afh[4], afl[4], bfh[4], bfl[4];
        #pragma unroll
        for (int mf = 0; mf < 4; mf++) {
            afh[mf] = *(const s16x8*)&Ah[(wm * 64 + mf * 16 + l15) * 40 + lh * 8];
            afl[mf] = *(const s16x8*)&Al[(wm * 64 + mf * 16 + l15) * 40 + lh * 8];
        }
        #pragma unroll
        for (int nf = 0; nf < 4; nf++) {
            bfh[nf] = *(const s16x8*)&Bh[(wn * 64 + nf * 16 + l15) * 40 + lh * 8];
            bfl[nf] = *(const s16x8*)&Bl[(wn * 64 + nf * 16 + l15) * 40 + lh * 8];
        }
        #pragma unroll
        for (int mf = 0; mf < 4; mf++)
            #pragma unroll
            for (int nf = 0; nf < 4; nf++) {
                acc[mf][nf] = mfma16(afh[mf], bfh[nf], acc[mf][nf]);
                acc[mf][nf] = mfma16(afl[mf], bfh[nf], acc[mf][nf]);
                acc[mf][nf] = mfma16(afh[mf], bfl[nf], acc[mf][nf]);
            }
    }
    #pragma unroll
    for (int mf = 0; mf < 4; mf++)
        #pragma unroll
        for (int nf = 0; nf < 4; nf++)
            #pragma unroll
            for (int r = 0; r < 4; r++) {
                int row = m0 + wm * 64 + mf * 16 + lh * 4 + r;
                int col = n0 + wn * 64 + nf * 16 + l15;
                Cout[(size_t)row * N + col] = acc[mf][nf][r] + bias[col];
            }
}

// ---------------- RoPE + split + transpose/pack ----------------
__global__ __launch_bounds__(256) void k_rope_pack(const float* __restrict__ qkv,
                                                   const float* __restrict__ sinT,
                                                   const float* __restrict__ cosT,
                                                   __bf16* __restrict__ q_hi, __bf16* __restrict__ q_lo,
                                                   __bf16* __restrict__ k_hi, __bf16* __restrict__ k_lo,
                                                   __bf16* __restrict__ v_hi, __bf16* __restrict__ v_lo) {
    const int bh = blockIdx.x >> 4, tc = blockIdx.x & 15;
    const int b = bh >> 4, h = bh & 15;
    const int t0 = tc * 64;
    __shared__ float vt[64 * 72];
    const int tid = threadIdx.x;
    const int tl = tid >> 2, dq = (tid & 3) * 8;
    const int t = t0 + tl;
    const size_t base = ((size_t)(b * T_ + t) * 3) * C_ + h * 64;

    f32x4 s0 = *(const f32x4*)(sinT + t * 64 + dq);
    f32x4 s1 = *(const f32x4*)(sinT + t * 64 + dq + 4);
    f32x4 c0 = *(const f32x4*)(cosT + t * 64 + dq);
    f32x4 c1 = *(const f32x4*)(cosT + t * 64 + dq + 4);

    {
        f32x4 ql0 = *(const f32x4*)(qkv + base + dq);
        f32x4 ql1 = *(const f32x4*)(qkv + base + dq + 4);
        f32x4 qu0 = *(const f32x4*)(qkv + base + dq + 32);
        f32x4 qu1 = *(const f32x4*)(qkv + base + dq + 36);
        f32x4 qa0 = (ql0 * c0 - qu0 * s0) * 0.125f;
        f32x4 qa1 = (ql1 * c1 - qu1 * s1) * 0.125f;
        f32x4 qb0 = (qu0 * c0 + ql0 * s0) * 0.125f;
        f32x4 qb1 = (qu1 * c1 + ql1 * s1) * 0.125f;
        size_t qi = ((size_t)bh * T_ + t) * 64 + dq;
        s16x8 hi, lo;
        split_pack(qa0, qa1, hi, lo);
        *(s16x8*)(q_hi + qi) = hi; *(s16x8*)(q_lo + qi) = lo;
        split_pack(qb0, qb1, hi, lo);
        *(s16x8*)(q_hi + qi + 32) = hi; *(s16x8*)(q_lo + qi + 32) = lo;
        f32x4 kl0 = *(const f32x4*)(qkv + base + C_ + dq);
        f32x4 kl1 = *(const f32x4*)(qkv + base + C_ + dq + 4);
        f32x4 ku0 = *(const f32x4*)(qkv + base + C_ + dq + 32);
        f32x4 ku1 = *(const f32x4*)(qkv + base + C_ + dq + 36);
        f32x4 ka0 = kl0 * c0 - ku0 * s0;
        f32x4 ka1 = kl1 * c1 - ku1 * s1;
        f32x4 kb0 = ku0 * c0 + kl0 * s0;
        f32x4 kb1 = ku1 * c1 + kl1 * s1;
        split_pack(ka0, ka1, hi, lo);
        *(s16x8*)(k_hi + qi) = hi; *(s16x8*)(k_lo + qi) = lo;
        split_pack(kb0, kb1, hi, lo);
        *(s16x8*)(k_hi + qi + 32) = hi; *(s16x8*)(k_lo + qi + 32) = lo;
    }
    {
        f32x4 vl0 = *(const f32x4*)(qkv + base + 2 * C_ + dq);
        f32x4 vl1 = *(const f32x4*)(qkv + base + 2 * C_ + dq + 4);
        f32x4 vu0 = *(const f32x4*)(qkv + base + 2 * C_ + dq + 32);
        f32x4 vu1 = *(const f32x4*)(qkv + base + 2 * C_ + dq + 36);
        #pragma unroll
        for (int j = 0; j < 4; j++) {
            vt[tl * 72 + dq + j]      = vl0[j];
            vt[tl * 72 + dq + 4 + j]  = vl1[j];
            vt[tl * 72 + dq + 32 + j] = vu0[j];
            vt[tl * 72 + dq + 36 + j] = vu1[j];
        }
    }
    __syncthreads();
    const int d = tid >> 2, tq = (tid & 3) * 16;
    bf16x8 h0, h1, l0, l1;
    #pragma unroll
    for (int i = 0; i < 8; i++) {
        float va = vt[(tq + i) * 72 + d];
        float vb = vt[(tq + 8 + i) * 72 + d];
        __bf16 xa = (__bf16)va; h0[i] = xa; l0[i] = (__bf16)(va - (float)xa);
        __bf16 xb = (__bf16)vb; h1[i] = xb; l1[i] = (__bf16)(vb - (float)xb);
    }
    size_t vi = ((size_t)bh * 64 + d) * T_ + t0 + tq;
    *(s16x8*)(v_hi + vi)     = __builtin_bit_cast(s16x8, h0);
    *(s16x8*)(v_hi + vi + 8) = __builtin_bit_cast(s16x8, h1);
    *(s16x8*)(v_lo + vi)     = __builtin_bit_cast(s16x8, l0);
    *(s16x8*)(v_lo + vi + 8) = __builtin_bit_cast(s16x8, l1);
}

// ---------------- Attention ----------------
// Block: 512 threads (8 waves), one (b,h) x 16 q-rows. LDS: 16x1024 f32 scores (XOR-swizzled).
// Latency-oriented: bias prefetched to regs, P kept in regs through softmax,
// normalization deferred to the PV epilogue, attn written nontemporal during PV.
__global__ __launch_bounds__(512, 4) void k_attn(const __bf16* __restrict__ q_hi, const __bf16* __restrict__ q_lo,
                                                 const __bf16* __restrict__ k_hi, const __bf16* __restrict__ k_lo,
                                                 const __bf16* __restrict__ v_hi, const __bf16* __restrict__ v_lo,
                                                 const float* __restrict__ rel_bias,
                                                 const float* __restrict__ gains,
                                                 float* __restrict__ attn_out,
                                                 float* __restrict__ ctx_out) {
    // bijective XCD swizzle: 4096 blocks, 8 XCDs, 512 per chunk
    const int wg = (blockIdx.x & 7) * 512 + (blockIdx.x >> 3);
    const int bh = wg >> 6, t0 = (wg & 63) * 16;
    const int h = bh & 15;
    __shared__ __attribute__((aligned(16))) float sc[16 * 1024];  // 64KB
    __shared__ float invbuf[16];
    const int tid = threadIdx.x, lane = tid & 63, w = tid >> 6;   // w = 0..7
    const int l15 = lane & 15, lh = lane >> 4;
    f32x4 zero = {0.f, 0.f, 0.f, 0.f};

    // ---- bias prefetch (issues before/with K loads; overlaps QK^T)
    float biasv[8][4];
    {
        const float* rbb = rel_bias + ((size_t)h * T_ + t0) * T_ + w * 128 + l15;
        #pragma unroll
        for (int nf = 0; nf < 8; nf++)
            #pragma unroll
            for (int r = 0; r < 4; r++)
                biasv[nf][r] = rbb[(size_t)(lh * 4 + r) * T_ + nf * 16];
    }

    // ---- Phase A: scores = (q*scale) @ k^T, 3-pass split. Wave w: s in [w*128, w*128+128)
    s16x8 aq0h, aq0l, aq1h, aq1l;
    {
        size_t qb = ((size_t)bh * T_ + t0 + l15) * 64 + lh * 8;
        aq0h = *(const s16x8*)(q_hi + qb); aq1h = *(const s16x8*)(q_hi + qb + 32);
        aq0l = *(const s16x8*)(q_lo + qb); aq1l = *(const s16x8*)(q_lo + qb + 32);
    }
    f32x4 acc[8];
    #pragma unroll
    for (int i = 0; i < 8; i++) acc[i] = zero;
    #pragma unroll
    for (int nf = 0; nf < 8; nf++) {
        int srow = w * 128 + nf * 16 + l15;
        size_t kb = ((size_t)bh * T_ + srow) * 64 + lh * 8;
        s16x8 kh0 = *(const s16x8*)(k_hi + kb), kh1 = *(const s16x8*)(k_hi + kb + 32);
        s16x8 kl0 = *(const s16x8*)(k_lo + kb), kl1 = *(const s16x8*)(k_lo + kb + 32);
        acc[nf] = mfma16(aq0h, kh0, acc[nf]);
        acc[nf] = mfma16(aq0l, kh0, acc[nf]);
        acc[nf] = mfma16(aq0h, kl0, acc[nf]);
        acc[nf] = mfma16(aq1h, kh1, acc[nf]);
        acc[nf] = mfma16(aq1l, kh1, acc[nf]);
        acc[nf] = mfma16(aq1h, kl1, acc[nf]);
    }
    #pragma unroll
    for (int nf = 0; nf < 8; nf++)
        #pragma unroll
        for (int r = 0; r < 4; r++) {
            int row = lh * 4 + r;
            int s = w * 128 + nf * 16 + l15;
            int xr = (row & 7) << 2;
            sc[row * 1024 + (s ^ xr)] = acc[nf][r] + biasv[nf][r];
        }
    __syncthreads();

    // ---- Phase B: softmax per row (32 threads/row); P kept in registers
    const int row = tid >> 5, seg = tid & 31;
    f32x4 p[8];
    float inv;
    {
        const int xr = (row & 7) << 2;
        float* scr = sc + row * 1024;
        float m = -3.4e38f;
        #pragma unroll
        for (int i = 0; i < 8; i++) {
            p[i] = *(const f32x4*)&scr[(i * 128 + seg * 4) ^ xr];
            m = fmaxf(m, fmaxf(fmaxf(p[i][0], p[i][1]), fmaxf(p[i][2], p[i][3])));
        }
        #pragma unroll
        for (int o = 16; o >= 1; o >>= 1) m = fmaxf(m, __shfl_xor(m, o));
        float lsum = 0.f;
        #pragma unroll
        for (int i = 0; i < 8; i++) {
            f32x4 v = p[i];
            v[0] = __expf(v[0] - m); v[1] = __expf(v[1] - m);
            v[2] = __expf(v[2] - m); v[3] = __expf(v[3] - m);
            p[i] = v;
            *(f32x4*)&scr[(i * 128 + seg * 4) ^ xr] = v;  // unnormalized exp for PV
            lsum += v[0] + v[1] + v[2] + v[3];
        }
        #pragma unroll
        for (int o = 16; o >= 1; o >>= 1) lsum += __shfl_xor(lsum, o);
        inv = 1.f / lsum;
        if (seg == 0) invbuf[row] = inv;
    }
    __syncthreads();

    // ---- Phase C: attn store (nontemporal, overlaps PV) + PV on unnormalized P
    {
        float* arow = attn_out + ((size_t)bh * T_ + t0 + row) * T_ + seg * 4;
        #pragma unroll
        for (int i = 0; i < 8; i++) {
            f32x4 v = p[i] * inv;
            __builtin_nontemporal_store(v, (f32x4*)(arow + i * 128));
        }
    }
    f32x4 cacc[4];
    #pragma unroll
    for (int i = 0; i < 4; i++) cacc[i] = zero;
    const int xs = (l15 & 7) << 2;
    #pragma unroll
    for (int ks = 0; ks < 4; ks++) {
        int sbase = w * 128 + ks * 32 + lh * 8;
        const float* ap = sc + l15 * 1024;
        f32x4 a0 = *(const f32x4*)&ap[(sbase) ^ xs];
        f32x4 a1 = *(const f32x4*)&ap[(sbase + 4) ^ xs];
        s16x8 ah, al; split_pack(a0, a1, ah, al);
        #pragma unroll
        for (int nf = 0; nf < 4; nf++) {
            size_t vb = ((size_t)bh * 64 + nf * 16 + l15) * T_ + sbase;
            s16x8 vh = *(const s16x8*)(v_hi + vb);
            s16x8 vl = *(const s16x8*)(v_lo + vb);
            cacc[nf] = mfma16(ah, vh, cacc[nf]);
            cacc[nf] = mfma16(al, vh, cacc[nf]);
            cacc[nf] = mfma16(ah, vl, cacc[nf]);
        }
    }
    __syncthreads();
    // scale partials by per-row inv, dump, reduce, apply gains, write ctx
    float invr[4];
    #pragma unroll
    for (int r = 0; r < 4; r++) invr[r] = invbuf[lh * 4 + r];
    #pragma unroll
    for (int nf = 0; nf < 4; nf++)
        #pragma unroll
        for (int r = 0; r < 4; r++)
            sc[w * 1024 + (lh * 4 + r) * 64 + nf * 16 + l15] = cacc[nf][r] * invr[r];
    __syncthreads();
    {
        int e0 = tid * 2;                       // 1024 outputs, 512 threads
        int crow = e0 >> 6, d = e0 & 63;
        f32x2 sm = *(const f32x2*)&sc[e0];
        #pragma unroll
        for (int w2 = 1; w2 < 8; w2++) sm += *(const f32x2*)&sc[w2 * 1024 + e0];
        float g = gains[h];
        sm[0] *= g; sm[1] *= g;
        *(f32x2*)(ctx_out + ((size_t)bh * T_ + t0 + crow) * 64 + d) = sm;
    }
}

extern "C" void kernel_launch(void* const* d_in, const int* in_sizes, int n_in,
                              void* d_out, int out_size, void* d_ws, size_t ws_size,
                              hipStream_t stream) {
    const float* x        = (const float*)d_in[0];
    const float* qkv_w    = (const float*)d_in[1];
    const float* qkv_b    = (const float*)d_in[2];
    const float* out_w    = (const float*)d_in[3];
    const float* out_b    = (const float*)d_in[4];
    const float* rel_bias = (const float*)d_in[5];
    const float* sinT     = (const float*)d_in[6];
    const float* cosT     = (const float*)d_in[7];
    const float* gains    = (const float*)d_in[8];

    float* out  = (float*)d_out;                       // [B,T,C]
    float* ctx  = out + (size_t)B_ * T_ * C_;          // [B,H,T,D]
    float* attn = ctx + (size_t)B_ * H_ * T_ * D_;     // [B,H,T,T]

    char* ws = (char*)d_ws;
    __bf16* q_hi = (__bf16*)(ws);                      // 8 MB [B,H,T,D]
    __bf16* q_lo = (__bf16*)(ws + ((size_t)8 << 20));
    __bf16* k_hi = (__bf16*)(ws + ((size_t)16 << 20));
    __bf16* k_lo = (__bf16*)(ws + ((size_t)24 << 20));
    __bf16* v_hi = (__bf16*)(ws + ((size_t)32 << 20)); // [B,H,D,T]
    __bf16* v_lo = (__bf16*)(ws + ((size_t)40 << 20));
    // qkv f32 intermediate [B,T,3C] (48 MB) lives in the attn output region:
    // fully consumed by k_rope_pack before k_attn writes attn.
    float* qkvF = attn;

    // QKV: [4096,1024] @ [3072,1024]^T + qkv_b -> qkvF [4096,3072]  (3-pass split)
    k_gemm_3p<0><<<dim3(24, 32), 256, 0, stream>>>(x, qkv_w, qkv_b, qkvF, 3072, 1024);
    // RoPE + split + pack
    k_rope_pack<<<1024, 256, 0, stream>>>(qkvF, sinT, cosT, q_hi, q_lo, k_hi, k_lo, v_hi, v_lo);
    // Attention (writes attn f32, ctx f32)
    k_attn<<<4096, 512, 0, stream>>>(q_hi, q_lo, k_hi, k_lo, v_hi, v_lo,
                                     rel_bias, gains, attn, ctx);
    // Output projection: merged(=ctx perm) [4096,1024] @ [1024,1024]^T + out_b -> out
    k_gemm_3p<1><<<dim3(8, 32), 256, 0, stream>>>(ctx, out_w, out_b, out, 1024, 1024);
}